// Round 7
// baseline (8582.618 us; speedup 1.0000x reference)
//
#include <hip/hip_runtime.h>
#include <cstdint>
#include <cstddef>

// Decoder (DA-RNN): B=512, T=256, E=D=256.
// Round 9: phase-merge + wave role-specialization + Ph2 LDS prefetch.
// Base = R8/R6 verified kernel (5040us k_scan, conflicts fixed). Changes:
//  (1) q computed FULL-k by 256 threads (both rows) -> Qs=exp(2q) written
//      directly: qpart round-trip + combine + one barrier eliminated (5->4).
//  (2) phase A role split: 4 q-waves || 8 gates-waves (k-split 2, complete
//      outputs) || 4 stager-waves prefetching 96KB of this step's Ph2 slice
//      into LDS (chunks {0..5,16..21} x 2 rows) - overlaps the L2-thrashing
//      Ph2 stream with phase-A compute (async-stage, byte-neutral).
//  (3) phase B reads 6/16 chunks from LDS, 10 from global.
// Register-bulk approaches remain dead (R3-R5 spilled). LDS ~139KB, 1 blk/CU.

typedef _Float16 half8 __attribute__((ext_vector_type(8)));
typedef _Float16 half4v __attribute__((ext_vector_type(4)));
typedef _Float16 half2v __attribute__((ext_vector_type(2)));

__device__ __forceinline__ float rcpf_(float x) { return __builtin_amdgcn_rcpf(x); }
__device__ __forceinline__ float sigmoidf_(float x) { return rcpf_(1.f + __expf(-x)); }
__device__ __forceinline__ float tanhf_(float x) { return 1.f - 2.f * rcpf_(1.f + __expf(2.f * x)); }

#if defined(__has_builtin)
#if __has_builtin(__builtin_amdgcn_fdot2)
#define HAS_FDOT2 1
#endif
#endif
#ifndef HAS_FDOT2
#define HAS_FDOT2 0
#endif

__device__ __forceinline__ float fdot2_(half2v a, half2v b, float c) {
#if HAS_FDOT2
  return __builtin_amdgcn_fdot2(a, b, c, false);
#else
  return fmaf((float)a[0], (float)b[0], fmaf((float)a[1], (float)b[1], c));
#endif
}

__device__ __forceinline__ float dot8_(half8 w, half8 h, float acc) {
  acc = fdot2_(__builtin_shufflevector(w, w, 0, 1), __builtin_shufflevector(h, h, 0, 1), acc);
  acc = fdot2_(__builtin_shufflevector(w, w, 2, 3), __builtin_shufflevector(h, h, 2, 3), acc);
  acc = fdot2_(__builtin_shufflevector(w, w, 4, 5), __builtin_shufflevector(h, h, 4, 5), acc);
  acc = fdot2_(__builtin_shufflevector(w, w, 6, 7), __builtin_shufflevector(h, h, 6, 7), acc);
  return acc;
}

// ---------------- prep kernels ----------------

// wT[e*256+f] = attn_w1[f*768 + 512 + e]   (transposed w1_enc, fp32)
__global__ void k_prep_wT(const float* __restrict__ w1, float* __restrict__ wT) {
  int id = blockIdx.x * 256 + threadIdx.x;
  int e = id >> 8, f = id & 255;
  wT[id] = w1[f * 768 + 512 + e];
}

// x -> fp16 (4 elems/thread), layout unchanged [b][t][e]
__global__ void k_prep_xh(const float* __restrict__ x, _Float16* __restrict__ xh) {
  int id = blockIdx.x * 256 + threadIdx.x;
  float4 v = reinterpret_cast<const float4*>(x)[id];
  half4v h;
  h[0] = (_Float16)v.x; h[1] = (_Float16)v.y; h[2] = (_Float16)v.z; h[3] = (_Float16)v.w;
  reinterpret_cast<half4v*>(xh)[id] = h;
}

// w1hcF[(c*256 + e)*8 + m] = w1[e*768 + c*8 + m], c in [0,64)  (full-k q rows)
// k_scan q-thread e reads chunk c at half8 index c*256+e (lane-consecutive).
__global__ void k_prep_w1hcQ(const float* __restrict__ w1, _Float16* __restrict__ o) {
  int id = blockIdx.x * 256 + threadIdx.x;  // 131072 total
  int m = id & 7, e = (id >> 3) & 255, c = id >> 11;
  o[id] = (_Float16)w1[e * 768 + c * 8 + m];
}

// whh2[(((kh*16 + c)*4 + js)*256 + jo)*8 + m] = Whh[(js*256+jo)*256 + kh*128 + c*8 + m]
// (gate thread (jo, kh) computes outputs js*256+jo over k in [kh*128,+128))
__global__ void k_prep_whhG(const float* __restrict__ whh, _Float16* __restrict__ o) {
  int id = blockIdx.x * 256 + threadIdx.x;  // 262144 total
  int m = id & 7, jo = (id >> 3) & 255, js = (id >> 11) & 3;
  int c = (id >> 13) & 15, kh = id >> 17;
  int j = js * 256 + jo, k = kh * 128 + c * 8 + m;
  o[id] = (_Float16)whh[j * 256 + k];
}

// xf[b*256+t] = sum_e x[b,t,e] * fcw[e]   (fp32)
__global__ __launch_bounds__(256) void k_xf(const float* __restrict__ x,
                                            const float* __restrict__ fcw,
                                            float* __restrict__ xf) {
  __shared__ float xl[16][256];
  __shared__ float fw[256];
  __shared__ float part[16][17];
  const int tid = threadIdx.x;
  const int m0 = blockIdx.x * 16;
  fw[tid] = fcw[tid];
#pragma unroll
  for (int r = 0; r < 16; ++r) xl[r][tid] = x[(size_t)(m0 + r) * 256 + tid];
  __syncthreads();
  int r = tid >> 4, p = tid & 15;
  float s = 0.f;
#pragma unroll
  for (int u = 0; u < 16; ++u) s = fmaf(xl[r][p * 16 + u], fw[p * 16 + u], s);
  part[r][p] = s;
  __syncthreads();
  if (tid < 16) {
    float t = 0.f;
#pragma unroll
    for (int p2 = 0; p2 < 16; ++p2) t += part[tid][p2];
    xf[m0 + tid] = t;
  }
}

// enc_proj GEMM + bias, store P=exp(2*encp) fp16 in layout [b][e/8][t][e%8]
__global__ __launch_bounds__(256) void k_encp(const float* __restrict__ x,
                                              const float* __restrict__ wT,
                                              const float* __restrict__ b1,
                                              _Float16* __restrict__ Ph2) {
  __shared__ __align__(16) float xl[16][256];
  const int tid = threadIdx.x;
  const int m0 = blockIdx.x * 16;
#pragma unroll
  for (int r = 0; r < 16; ++r) xl[r][tid] = x[(size_t)(m0 + r) * 256 + tid];
  __syncthreads();
  float acc[16];
#pragma unroll
  for (int r = 0; r < 16; ++r) acc[r] = 0.f;
  for (int e = 0; e < 256; e += 4) {
    float w0 = wT[(e + 0) * 256 + tid];
    float w1_ = wT[(e + 1) * 256 + tid];
    float w2_ = wT[(e + 2) * 256 + tid];
    float w3_ = wT[(e + 3) * 256 + tid];
#pragma unroll
    for (int r = 0; r < 16; ++r) {
      float4 xv = *reinterpret_cast<const float4*>(&xl[r][e]);
      acc[r] = fmaf(xv.x, w0, acc[r]);
      acc[r] = fmaf(xv.y, w1_, acc[r]);
      acc[r] = fmaf(xv.z, w2_, acc[r]);
      acc[r] = fmaf(xv.w, w3_, acc[r]);
    }
  }
  float bb = b1[tid];
  const int e = tid;
#pragma unroll
  for (int r = 0; r < 16; ++r) {
    int m = m0 + r, b = m >> 8, t = m & 255;
    float p = __expf(2.f * (acc[r] + bb));
    Ph2[((size_t)(b * 32 + (e >> 3)) * 256 + t) * 8 + (e & 7)] = (_Float16)p;
  }
}

#define SC1(pv, c) { \
  float4 qa = q4[2*(c)], wa = w4[2*(c)]; \
  sacc0 = fmaf(wa.x, rcpf_(fmaf((float)pv[0], qa.x, 1.f)), sacc0); \
  sacc1 = fmaf(wa.y, rcpf_(fmaf((float)pv[1], qa.y, 1.f)), sacc1); \
  sacc0 = fmaf(wa.z, rcpf_(fmaf((float)pv[2], qa.z, 1.f)), sacc0); \
  sacc1 = fmaf(wa.w, rcpf_(fmaf((float)pv[3], qa.w, 1.f)), sacc1); \
  float4 qb = q4[2*(c)+1], wb = w4[2*(c)+1]; \
  sacc0 = fmaf(wb.x, rcpf_(fmaf((float)pv[4], qb.x, 1.f)), sacc0); \
  sacc1 = fmaf(wb.y, rcpf_(fmaf((float)pv[5], qb.y, 1.f)), sacc1); \
  sacc0 = fmaf(wb.z, rcpf_(fmaf((float)pv[6], qb.z, 1.f)), sacc0); \
  sacc1 = fmaf(wb.w, rcpf_(fmaf((float)pv[7], qb.w, 1.f)), sacc1); }

// ---------------- the scan ----------------
// grid 256 x 1024 threads; wg owns 2 batch rows; 4 barriers/step.
__global__ __launch_bounds__(1024, 4) void k_scan(
    const _Float16* __restrict__ Ph2, const _Float16* __restrict__ xh,
    const _Float16* __restrict__ w1hcQ, const _Float16* __restrict__ whhG,
    const float* __restrict__ xf, const float* __restrict__ y_hist,
    const float* __restrict__ w2g, const float* __restrict__ Wih,
    const float* __restrict__ bih, const float* __restrict__ bhh,
    const float* __restrict__ fcw, const float* __restrict__ fcb,
    const float* __restrict__ fcfw, const float* __restrict__ fcfb,
    float* __restrict__ out) {
  __shared__ __align__(16) float hc[2][512];        // fp32 [g][ h | c ]
  __shared__ __align__(16) _Float16 hcH[2][512];    // fp16 mirror for dot2
  __shared__ __align__(16) float Qs[2][256];        // exp(2q)
  __shared__ __align__(16) float spart[2][2][256];  // [eh][g][t]
  __shared__ __align__(16) float ealpha[2][256];
  __shared__ __align__(16) float gpart[2][2][1024]; // [kh][g][j]
  __shared__ __align__(16) _Float16 PhL[2][12][256][8];  // 96KB Ph2 stage; aliased post-loop as cpart
  __shared__ __align__(16) float w2l[256];
  __shared__ __align__(16) float Wihl[1024];
  __shared__ __align__(16) float bl[1024];
  __shared__ __align__(16) float xfL[2][256];
  __shared__ __align__(16) float yhL[2][256];
  __shared__ float redA[8], redB[8];

  const int tid = threadIdx.x;
  const int b0 = blockIdx.x * 2;
  const int lo = tid & 255;
  const int wv = tid >> 6, lane = tid & 63;

  // ---- init ----
  ((float*)hc)[tid] = 0.f;
  ((_Float16*)hcH)[tid] = (_Float16)0.f;
  if (tid < 256) w2l[tid] = w2g[tid];
  Wihl[tid] = Wih[tid];
  bl[tid] = bih[tid] + bhh[tid];
  if (tid < 512) {
    int gi = tid >> 8, ti = tid & 255;
    xfL[gi][ti] = xf[(size_t)(b0 + gi) * 256 + ti];
    yhL[gi][ti] = y_hist[(size_t)(b0 + gi) * 256 + ti];
  }
  __syncthreads();
  float w2sum = 0.f;
  for (int e2 = 0; e2 < 256; ++e2) w2sum += w2l[e2];
  const float fcb0 = fcb[0];
  const float fcwy = fcw[256];

  // role constants
  // q (tid<256): e = tid, full k, both rows
  const half8* wqF = reinterpret_cast<const half8*>(w1hcQ) + tid;   // [c*256], c<64
  // gates (256<=tid<768): u = tid-256: jo = u&255, kh = u>>8
  const int ug = (tid - 256) & 1023;   // valid only for gates role
  const int jo = ug & 255, kh = (ug >> 8) & 1;
  const half8* wg2 = reinterpret_cast<const half8*>(whhG) + kh * 16384 + jo;
  // stagers (tid>=768): v = tid-768: gst = v>>7, wst = v&127
  const int vs = (tid - 768) & 255;
  const int gst = vs >> 7, wst = vs & 127;
  const half8* pgS = reinterpret_cast<const half8*>(Ph2) + ((size_t)(b0 + gst) * 32) * 256 + wst;
  half8* phlS = reinterpret_cast<half8*>(&PhL[0][0][0][0]) + gst * 12 * 256 + wst;
  // scores (all): gs = tid>>9, eh = (tid>>8)&1, t = lo
  const int gs = tid >> 9, eh = (tid >> 8) & 1;
  const half8* prow = reinterpret_cast<const half8*>(Ph2) +
                      ((size_t)((b0 + gs) * 32 + eh * 16)) * 256 + lo;
  const half8* phlR = reinterpret_cast<const half8*>(&PhL[0][0][0][0]) +
                      (gs * 12 + eh * 6) * 256 + lo;
  // combine/LSTM (tid<512): gp
  const int gp = (tid >> 8) & 1;

#pragma unroll 1
  for (int s = 0; s < 256; ++s) {
    // ---- phase A: q full-k -> Qs  ||  gates (k-split 2)  ||  Ph2 staging ----
    if (tid < 256) {
      float a0 = 0.f, a1 = 0.f;
      const half8* hp0 = reinterpret_cast<const half8*>(&hcH[0][0]);
      const half8* hp1 = reinterpret_cast<const half8*>(&hcH[1][0]);
#pragma unroll 8
      for (int c = 0; c < 64; ++c) {
        half8 w = wqF[c * 256];
        a0 = dot8_(w, hp0[c], a0);   // broadcast LDS reads
        a1 = dot8_(w, hp1[c], a1);
      }
      Qs[0][tid] = __expf(2.f * a0);
      Qs[1][tid] = __expf(2.f * a1);
    } else if (tid < 768) {
      float ac0[4], ac1[4];
#pragma unroll
      for (int m = 0; m < 4; ++m) { ac0[m] = 0.f; ac1[m] = 0.f; }
      const half8* hg0 = reinterpret_cast<const half8*>(&hcH[0][kh * 128]);
      const half8* hg1 = reinterpret_cast<const half8*>(&hcH[1][kh * 128]);
#pragma unroll 4
      for (int c = 0; c < 16; ++c) {
        half8 h0 = hg0[c];   // broadcast
        half8 h1 = hg1[c];
#pragma unroll
        for (int js = 0; js < 4; ++js) {
          half8 w = wg2[c * 1024 + js * 256];
          ac0[js] = dot8_(w, h0, ac0[js]);
          ac1[js] = dot8_(w, h1, ac1[js]);
        }
      }
#pragma unroll
      for (int js = 0; js < 4; ++js) {
        gpart[kh][0][js * 256 + jo] = ac0[js];
        gpart[kh][1][js * 256 + jo] = ac1[js];
      }
    } else {
      // stage Ph2 chunks {0..5} and {16..21} for row gst into PhL
      half8 s0 = __builtin_nontemporal_load(pgS + 0 * 256);
      half8 s1 = __builtin_nontemporal_load(pgS + 0 * 256 + 128);
      half8 s2 = __builtin_nontemporal_load(pgS + 1 * 256);
      half8 s3 = __builtin_nontemporal_load(pgS + 1 * 256 + 128);
      half8 s4 = __builtin_nontemporal_load(pgS + 2 * 256);
      half8 s5 = __builtin_nontemporal_load(pgS + 2 * 256 + 128);
      half8 s6 = __builtin_nontemporal_load(pgS + 3 * 256);
      half8 s7 = __builtin_nontemporal_load(pgS + 3 * 256 + 128);
      half8 s8 = __builtin_nontemporal_load(pgS + 4 * 256);
      half8 s9 = __builtin_nontemporal_load(pgS + 4 * 256 + 128);
      half8 sa = __builtin_nontemporal_load(pgS + 5 * 256);
      half8 sb = __builtin_nontemporal_load(pgS + 5 * 256 + 128);
      phlS[0 * 256] = s0;  phlS[0 * 256 + 128] = s1;
      phlS[1 * 256] = s2;  phlS[1 * 256 + 128] = s3;
      phlS[2 * 256] = s4;  phlS[2 * 256 + 128] = s5;
      phlS[3 * 256] = s6;  phlS[3 * 256 + 128] = s7;
      phlS[4 * 256] = s8;  phlS[4 * 256 + 128] = s9;
      phlS[5 * 256] = sa;  phlS[5 * 256 + 128] = sb;
      half8 t0 = __builtin_nontemporal_load(pgS + 16 * 256);
      half8 t1 = __builtin_nontemporal_load(pgS + 16 * 256 + 128);
      half8 t2 = __builtin_nontemporal_load(pgS + 17 * 256);
      half8 t3 = __builtin_nontemporal_load(pgS + 17 * 256 + 128);
      half8 t4 = __builtin_nontemporal_load(pgS + 18 * 256);
      half8 t5 = __builtin_nontemporal_load(pgS + 18 * 256 + 128);
      half8 t6 = __builtin_nontemporal_load(pgS + 19 * 256);
      half8 t7 = __builtin_nontemporal_load(pgS + 19 * 256 + 128);
      half8 t8 = __builtin_nontemporal_load(pgS + 20 * 256);
      half8 t9 = __builtin_nontemporal_load(pgS + 20 * 256 + 128);
      half8 ta = __builtin_nontemporal_load(pgS + 21 * 256);
      half8 tb = __builtin_nontemporal_load(pgS + 21 * 256 + 128);
      phlS[6 * 256] = t0;   phlS[6 * 256 + 128] = t1;
      phlS[7 * 256] = t2;   phlS[7 * 256 + 128] = t3;
      phlS[8 * 256] = t4;   phlS[8 * 256 + 128] = t5;
      phlS[9 * 256] = t6;   phlS[9 * 256 + 128] = t7;
      phlS[10 * 256] = t8;  phlS[10 * 256 + 128] = t9;
      phlS[11 * 256] = ta;  phlS[11 * 256 + 128] = tb;
    }
    __syncthreads();  // B1

    // ---- phase B: scores, e-split 2; 6 chunks from LDS + 10 from global ----
    float sacc0 = 0.f, sacc1 = 0.f;
    {
      const float4* q4 = reinterpret_cast<const float4*>(&Qs[gs][eh * 128]);
      const float4* w4 = reinterpret_cast<const float4*>(&w2l[eh * 128]);
      half8 g6 = __builtin_nontemporal_load(prow + 6 * 256);
      half8 g7 = __builtin_nontemporal_load(prow + 7 * 256);
      half8 g8 = __builtin_nontemporal_load(prow + 8 * 256);
      half8 g9 = __builtin_nontemporal_load(prow + 9 * 256);
      half8 ga = __builtin_nontemporal_load(prow + 10 * 256);
      half8 gb = __builtin_nontemporal_load(prow + 11 * 256);
      half8 gc = __builtin_nontemporal_load(prow + 12 * 256);
      half8 gd = __builtin_nontemporal_load(prow + 13 * 256);
      half8 ge = __builtin_nontemporal_load(prow + 14 * 256);
      half8 gf = __builtin_nontemporal_load(prow + 15 * 256);
      {
        half8 l0 = phlR[0 * 256]; SC1(l0, 0)
        half8 l1 = phlR[1 * 256]; SC1(l1, 1)
        half8 l2 = phlR[2 * 256]; SC1(l2, 2)
        half8 l3 = phlR[3 * 256]; SC1(l3, 3)
        half8 l4 = phlR[4 * 256]; SC1(l4, 4)
        half8 l5 = phlR[5 * 256]; SC1(l5, 5)
      }
      SC1(g6, 6) SC1(g7, 7) SC1(g8, 8) SC1(g9, 9) SC1(ga, 10)
      SC1(gb, 11) SC1(gc, 12) SC1(gd, 13) SC1(ge, 14) SC1(gf, 15)
    }
    spart[eh][gs][lo] = sacc0 + sacc1;
    __syncthreads();  // B2

    // ---- phase C: combine + softmax reduce (tid < 512) ----
    if (tid < 512) {
      float sc = w2sum - 2.f * (spart[0][gp][lo] + spart[1][gp][lo]);
      float ea = __expf(sc);  // no max-sub: |sc| <= ~21, fp32-safe
      ealpha[gp][lo] = ea;
      float ef = ea * xfL[gp][lo];
      float es = ea;
#pragma unroll
      for (int off = 32; off > 0; off >>= 1) {
        es += __shfl_xor(es, off);
        ef += __shfl_xor(ef, off);
      }
      if (lane == 0) { redA[wv] = es; redB[wv] = ef; }
    }
    __syncthreads();  // B3

    // ---- phase D: LSTM pointwise (tid < 512) ----
    if (tid < 512) {
      float es = (gp == 0) ? (redA[0] + redA[1] + redA[2] + redA[3])
                           : (redA[4] + redA[5] + redA[6] + redA[7]);
      float ef = (gp == 0) ? (redB[0] + redB[1] + redB[2] + redB[3])
                           : (redB[4] + redB[5] + redB[6] + redB[7]);
      float yt = ef * rcpf_(es) + fmaf(yhL[gp][s], fcwy, fcb0);
      float gi = fmaf(yt, Wihl[lo], bl[lo]);
      float gf = fmaf(yt, Wihl[256 + lo], bl[256 + lo]);
      float gc = fmaf(yt, Wihl[512 + lo], bl[512 + lo]);
      float go = fmaf(yt, Wihl[768 + lo], bl[768 + lo]);
      gi += gpart[0][gp][lo] + gpart[1][gp][lo];
      gf += gpart[0][gp][256 + lo] + gpart[1][gp][256 + lo];
      gc += gpart[0][gp][512 + lo] + gpart[1][gp][512 + lo];
      go += gpart[0][gp][768 + lo] + gpart[1][gp][768 + lo];
      float iv = sigmoidf_(gi), fv = sigmoidf_(gf), gv = tanhf_(gc), ov = sigmoidf_(go);
      float cold = hc[gp][256 + lo];
      float cn = fmaf(fv, cold, iv * gv);
      float hn = ov * tanhf_(cn);
      hc[gp][lo] = hn;
      hc[gp][256 + lo] = cn;
      hcH[gp][lo] = (_Float16)hn;
      hcH[gp][256 + lo] = (_Float16)cn;
    }
    __syncthreads();  // B4
  }

  // ---- epilogue: context from step-255 ealpha, then out = [h|ctx].fcf ----
  // read last-step softmax sums BEFORE redA/redB get reused
  const float rsA = rcpf_(redA[0] + redA[1] + redA[2] + redA[3]);
  const float rsB = rcpf_(redA[4] + redA[5] + redA[6] + redA[7]);

  float* cpartF = reinterpret_cast<float*>(&PhL[0][0][0][0]);  // 32KB <= 96KB stage
  {
    const int gc2 = tid >> 9, t16 = (tid >> 5) & 15, l5 = tid & 31;
    const half8* xrow = reinterpret_cast<const half8*>(xh) +
                        ((size_t)(b0 + gc2) * 256 + t16 * 16) * 32 + l5;
    float acx[8];
#pragma unroll
    for (int m = 0; m < 8; ++m) acx[m] = 0.f;
#pragma unroll 4
    for (int it = 0; it < 16; ++it) {
      float al = ealpha[gc2][t16 * 16 + it];
      half8 xv = xrow[it * 32];
#pragma unroll
      for (int m = 0; m < 8; ++m) acx[m] = fmaf(al, (float)xv[m], acx[m]);
    }
    float* dst = &cpartF[((gc2 * 16 + t16) * 256) + l5 * 8];
    *reinterpret_cast<float4*>(dst) = *reinterpret_cast<float4*>(&acx[0]);
    *reinterpret_cast<float4*>(dst + 4) = *reinterpret_cast<float4*>(&acx[4]);
  }
  __syncthreads();

  if (tid < 512) {
    float cv = 0.f;
#pragma unroll
    for (int u = 0; u < 16; ++u) cv += cpartF[((gp * 16 + u) * 256) + lo];
    cv *= (gp == 0) ? rsA : rsB;
    float hval = hc[gp][lo];
    float p0 = hval * fcfw[lo] + cv * fcfw[256 + lo];
    float p1 = hval * fcfw[512 + lo] + cv * fcfw[768 + lo];
#pragma unroll
    for (int off = 32; off > 0; off >>= 1) {
      p0 += __shfl_xor(p0, off);
      p1 += __shfl_xor(p1, off);
    }
    if (lane == 0) { redA[wv] = p0; redB[wv] = p1; }
  }
  __syncthreads();
  if (tid < 4) {
    int g2 = tid >> 1, o = tid & 1;
    const float* r = (o == 0) ? redA : redB;
    float v = fcfb[o] + r[g2 * 4 + 0] + r[g2 * 4 + 1] + r[g2 * 4 + 2] + r[g2 * 4 + 3];
    out[(b0 + g2) * 2 + o] = v;
  }
}

extern "C" void kernel_launch(void* const* d_in, const int* in_sizes, int n_in,
                              void* d_out, int out_size, void* d_ws, size_t ws_size,
                              hipStream_t stream) {
  (void)in_sizes; (void)n_in; (void)out_size; (void)ws_size;
  const float* x    = (const float*)d_in[0];
  const float* yh   = (const float*)d_in[1];
  const float* w1   = (const float*)d_in[2];
  const float* b1   = (const float*)d_in[3];
  const float* w2   = (const float*)d_in[4];
  /* d_in[5] attn_b2: softmax-invariant, unused */
  const float* Wih  = (const float*)d_in[6];
  const float* Whh  = (const float*)d_in[7];
  const float* bih  = (const float*)d_in[8];
  const float* bhh  = (const float*)d_in[9];
  const float* fcw  = (const float*)d_in[10];
  const float* fcb  = (const float*)d_in[11];
  const float* fcfw = (const float*)d_in[12];
  const float* fcfb = (const float*)d_in[13];
  float* out = (float*)d_out;

  char* ws = (char*)d_ws;
  _Float16* Ph2   = (_Float16*)(ws);                      // 67108864 B
  _Float16* xh    = (_Float16*)(ws + (size_t)67108864);   // 67108864 B
  float*    wT    = (float*)   (ws + (size_t)134217728);  // 262144 B
  _Float16* w1hcQ = (_Float16*)(ws + (size_t)134479872);  // 262144 B
  _Float16* whhG  = (_Float16*)(ws + (size_t)134742016);  // 524288 B
  float*    xf    = (float*)   (ws + (size_t)135266304);  // 524288 B
  // total: 135790592 B (~129.5 MB)

  k_prep_wT   <<<256,   256, 0, stream>>>(w1, wT);
  k_prep_xh   <<<32768, 256, 0, stream>>>(x, xh);
  k_prep_w1hcQ<<<512,   256, 0, stream>>>(w1, w1hcQ);
  k_prep_whhG <<<1024,  256, 0, stream>>>(Whh, whhG);
  k_xf        <<<8192,  256, 0, stream>>>(x, fcw, xf);
  k_encp      <<<8192,  256, 0, stream>>>(x, wT, b1, Ph2);
  k_scan      <<<256,  1024, 0, stream>>>(Ph2, xh, w1hcQ, whhG, xf, yh, w2, Wih,
                                          bih, bhh, fcw, fcb, fcfw, fcfb, out);
}